// Round 5
// baseline (201.158 us; speedup 1.0000x reference)
//
#include <hip/hip_runtime.h>
#include <hip/hip_bf16.h>

// Problem: B=8192, L=128, O=512, K=8, H=20
#define B_TOT 8192
#define O_DIM 512
#define L_DIM 128
#define K_DIM 8
#define H_DIM 20

#define TB 64      // b per block (4 tiles of 16)
#define TO 8       // o per block (4 waves x 2)
#define NTH 256
#define XPITCH 66  // halfs per xT column (odd dword count + XOR swizzle)

typedef short bf16x8 __attribute__((ext_vector_type(8)));
typedef float f32x4  __attribute__((ext_vector_type(4)));

// LDS carve (bytes, all 16B aligned):
// W2T [8 o][32 m][40 k] bf16 = 20480   (m=h_out rows, k=h_in; zero-padded)
// W1  [8 o][9 k][32 h] f32   = 9216    (h zero-padded 20..31)
// BB  [8 o][3][32] f32       = 3072    (b1,b2,W3; zero-padded)
// NS  [64 b][9] f32          = 2304    (noise tile, odd pitch)
// XT  [128 col][66] bf16     = 16896   (x transposed, swizzled)
#define OFF_W2T 0
#define OFF_W1  20480
#define OFF_BB  29696
#define OFF_NS  32768
#define OFF_XT  35072
#define SMEM_BYTES 51968   // 50.75 KB -> 3 blocks/CU

// tanh(x) = 1 - 2/(1+exp(2x)); saturates correctly at +/-inf.
__device__ __forceinline__ float fast_tanh(float x) {
    float e = __builtin_amdgcn_exp2f(x * 2.885390081777927f); // 2*log2(e)
    float r = __builtin_amdgcn_rcpf(1.0f + e);
    return 1.0f - 2.0f * r;
}
__device__ __forceinline__ unsigned short f2bf(float f) {  // round-half-up bf16
    unsigned u = __float_as_uint(f);
    return (unsigned short)((u + 0x8000u) >> 16);
}

__global__ __launch_bounds__(NTH, 3) void medil_fused(
    const float* __restrict__ x, const float* __restrict__ noise,
    const int* __restrict__ cause_idx,
    const float* __restrict__ W1, const float* __restrict__ b1,
    const float* __restrict__ W2, const float* __restrict__ b2,
    const float* __restrict__ W3, const float* __restrict__ b3,
    float* __restrict__ out)
{
    __shared__ __align__(16) char smem[SMEM_BYTES];
    unsigned short* w2t = (unsigned short*)(smem + OFF_W2T);
    float*          w1s = (float*)(smem + OFF_W1);
    float*          bbs = (float*)(smem + OFF_BB);
    float*          nss = (float*)(smem + OFF_NS);
    unsigned short* xts = (unsigned short*)(smem + OFF_XT);

    const int tid = threadIdx.x;
    const int o0 = (blockIdx.x & 63) * TO;   // o fast: x-tile reuse in L2
    const int b0 = (blockIdx.x >> 6) * TB;

    // ---- zero-fill padded weight regions (32 threads per o) ----
    {
        const int ol = tid >> 5, idx = tid & 31;
        unsigned int* w2z = (unsigned int*)(w2t + ol * 1280);
        #pragma unroll
        for (int z = 0; z < 20; ++z) w2z[idx + 32 * z] = 0u;
        float* w1o = w1s + ol * 288;
        #pragma unroll
        for (int z = 0; z < 9; ++z) w1o[idx + 32 * z] = 0.f;
        float* bbo = bbs + ol * 96;
        #pragma unroll
        for (int z = 0; z < 3; ++z) bbo[idx + 32 * z] = 0.f;
    }
    __syncthreads();
    // ---- fill weights ----
    {
        const int ol = tid >> 5, idx = tid & 31;
        const int o = o0 + ol;
        if (idx < 20) {
            unsigned short* w2o = w2t + ol * 1280;
            #pragma unroll
            for (int hi = 0; hi < 20; ++hi)   // W2T[m=idx][k=hi] = W2[hi][idx]
                w2o[idx * 40 + hi] = f2bf(W2[(size_t)o * 400 + hi * 20 + idx]);
            float* w1o = w1s + ol * 288;
            #pragma unroll
            for (int k = 0; k < 9; ++k)
                w1o[k * 32 + idx] = W1[(size_t)o * 180 + k * 20 + idx];
            float* bbo = bbs + ol * 96;
            bbo[idx]      = b1[o * H_DIM + idx];
            bbo[32 + idx] = b2[o * H_DIM + idx];
            bbo[64 + idx] = W3[o * H_DIM + idx];
        }
    }
    // ---- noise tile [64][9] ----
    {
        const int r = tid >> 3, oln = tid & 7;
        nss[r * 9 + oln]        = noise[(size_t)(b0 + r) * O_DIM + o0 + oln];
        nss[(r + 32) * 9 + oln] = noise[(size_t)(b0 + r + 32) * O_DIM + o0 + oln];
    }
    // ---- x tile: transposed bf16, XOR-swizzled rows ----
    {
        #pragma unroll
        for (int i = 0; i < 8; ++i) {
            int t = tid + NTH * i;            // 0..2047
            int c4 = t & 31, r = t >> 5;      // col4, local b row
            float4 v = *(const float4*)(x + (size_t)(b0 + r) * L_DIM + 4 * c4);
            float vv[4] = {v.x, v.y, v.z, v.w};
            #pragma unroll
            for (int s = 0; s < 4; ++s) {
                int col = 4 * c4 + s;
                xts[col * XPITCH + (r ^ (col & 31))] = f2bf(vv[s]);
            }
        }
    }
    __syncthreads();

    const int lane = tid & 63;
    const int wv   = tid >> 6;
    const int l15  = lane & 15;   // = b (B-frag n) / C col
    const int q    = lane >> 4;   // k-quad / C row group

    #pragma unroll 1
    for (int oo = 0; oo < 2; ++oo) {
        const int ol = __builtin_amdgcn_readfirstlane(2 * wv + oo);
        const int o  = o0 + ol;

        // ---- per-o register caches (amortized over 4 b-tiles) ----
        float w1r[9][8];                      // W1pad[k][8q+j]
        const float* w1o = w1s + ol * 288;
        #pragma unroll
        for (int k = 0; k < 9; ++k) {
            float4 lo = *(const float4*)(w1o + k * 32 + q * 8);
            float4 hi = *(const float4*)(w1o + k * 32 + q * 8 + 4);
            w1r[k][0] = lo.x; w1r[k][1] = lo.y; w1r[k][2] = lo.z; w1r[k][3] = lo.w;
            w1r[k][4] = hi.x; w1r[k][5] = hi.y; w1r[k][6] = hi.z; w1r[k][7] = hi.w;
        }
        const float* bbo = bbs + ol * 96;
        float b1r[8];
        {
            float4 lo = *(const float4*)(bbo + q * 8);
            float4 hi = *(const float4*)(bbo + q * 8 + 4);
            b1r[0] = lo.x; b1r[1] = lo.y; b1r[2] = lo.z; b1r[3] = lo.w;
            b1r[4] = hi.x; b1r[5] = hi.y; b1r[6] = hi.z; b1r[7] = hi.w;
        }
        float4 b2a = *(const float4*)(bbo + 32 + 4 * q);        // b2[4q+r]
        float4 b2b = *(const float4*)(bbo + 48 + 4 * q);        // b2[16+4q+r] (pad 0)
        float4 w3a = *(const float4*)(bbo + 64 + 4 * q);        // W3[4q+r]
        float4 w3b = *(const float4*)(bbo + 80 + 4 * q);        // W3[16+4q+r] (pad 0)
        // A-frags: W2T rows m=l15 / 16+l15, k-slice 8q..8q+7 (16B aligned)
        bf16x8 a2a = *(const bf16x8*)(w2t + ol * 1280 + l15 * 40 + q * 8);
        bf16x8 a2b = *(const bf16x8*)(w2t + ol * 1280 + (16 + l15) * 40 + q * 8);
        int cols[8];
        {
            const int* cip = cause_idx + o * K_DIM;
            #pragma unroll
            for (int k = 0; k < 8; ++k) cols[k] = cip[k];  // wave-uniform -> SGPRs
        }
        const float b3v = b3[o];

        #pragma unroll 1
        for (int bt = 0; bt < 4; ++bt) {
            const int row = bt * 16 + l15;
            // ---- layer 1 on VALU, output directly in B-frag layout (k=h=8q+j) ----
            float nz = nss[row * 9 + ol];
            float z[8];
            #pragma unroll
            for (int j = 0; j < 8; ++j) z[j] = fmaf(nz, w1r[0][j], b1r[j]);
            #pragma unroll
            for (int k = 0; k < 8; ++k) {
                int col = cols[k];
                unsigned short uh = xts[col * XPITCH + (row ^ (col & 31))];
                float xv = __uint_as_float(((unsigned)uh) << 16);
                #pragma unroll
                for (int j = 0; j < 8; ++j) z[j] = fmaf(xv, w1r[k + 1][j], z[j]);
            }
            union { bf16x8 v; unsigned int u[4]; } b2v;
            #pragma unroll
            for (int i = 0; i < 4; ++i) {
                float t0 = fast_tanh(z[2 * i]);
                float t1 = fast_tanh(z[2 * i + 1]);
                union { __hip_bfloat162 h; unsigned int u; } p;
                p.h = __float22bfloat162_rn(make_float2(t0, t1)); // low = even k
                b2v.u[i] = p.u;
            }
            // ---- layer 2 on MFMA (transposed): D[h_out][b] = W2T . a1T ----
            f32x4 zero = {0.f, 0.f, 0.f, 0.f};
            f32x4 c2a = __builtin_amdgcn_mfma_f32_16x16x32_bf16(a2a, b2v.v, zero, 0, 0, 0);
            f32x4 c2b = __builtin_amdgcn_mfma_f32_16x16x32_bf16(a2b, b2v.v, zero, 0, 0, 0);
            // ---- bias + tanh + layer 3 partial (rows 4q+r and 16+4q+r) ----
            float s = 0.f;
            s = fmaf(fast_tanh(c2a[0] + b2a.x), w3a.x, s);
            s = fmaf(fast_tanh(c2a[1] + b2a.y), w3a.y, s);
            s = fmaf(fast_tanh(c2a[2] + b2a.z), w3a.z, s);
            s = fmaf(fast_tanh(c2a[3] + b2a.w), w3a.w, s);
            s = fmaf(fast_tanh(c2b[0] + b2b.x), w3b.x, s);
            s = fmaf(fast_tanh(c2b[1] + b2b.y), w3b.y, s);
            s = fmaf(fast_tanh(c2b[2] + b2b.z), w3b.z, s);
            s = fmaf(fast_tanh(c2b[3] + b2b.w), w3b.w, s);
            // reduce over the 4 row-groups (lane bits 4,5)
            s += __shfl_xor(s, 16);
            s += __shfl_xor(s, 32);
            s += b3v;
            if (lane < 16)
                out[(size_t)(b0 + row) * O_DIM + o] = s;
        }
    }
}

extern "C" void kernel_launch(void* const* d_in, const int* in_sizes, int n_in,
                              void* d_out, int out_size, void* d_ws, size_t ws_size,
                              hipStream_t stream) {
    const float* x         = (const float*)d_in[0];
    const float* noise     = (const float*)d_in[1];
    const int*   cause_idx = (const int*)d_in[2];
    const float* W1        = (const float*)d_in[3];
    const float* b1        = (const float*)d_in[4];
    const float* W2        = (const float*)d_in[5];
    const float* b2        = (const float*)d_in[6];
    const float* W3        = (const float*)d_in[7];
    const float* b3        = (const float*)d_in[8];
    float* out = (float*)d_out;

    dim3 grid((B_TOT / TB) * (O_DIM / TO));   // 128 * 64 = 8192 blocks
    dim3 block(NTH);
    hipLaunchKernelGGL(medil_fused, grid, block, 0, stream,
                       x, noise, cause_idx, W1, b1, W2, b2, W3, b3, out);
}

// Round 7
// 194.899 us; speedup vs baseline: 1.0321x; 1.0321x over previous
//
#include <hip/hip_runtime.h>
#include <hip/hip_bf16.h>

// Problem: B=8192, L=128, O=512, K=8, H=20
#define B_TOT 8192
#define O_DIM 512
#define L_DIM 128
#define K_DIM 8
#define H_DIM 20

#define TO 8       // o per block (4 waves x 2)
#define TB 64      // b per block (4 tiles of 16)
#define NTH 256

typedef short bf16x8 __attribute__((ext_vector_type(8)));
typedef float f32x4  __attribute__((ext_vector_type(4)));

// ---- LDS byte offsets (16B aligned) ----
#define OFF_XP  0        // u32 [64 colpair][65 b]  16640  x bf16 pair-packed
#define OFF_W1T 16640    // u16 [8o][32 h][16 k]     8192  A-frag L1 (zero-padded)
#define OFF_W2T 24832    // u16 [8o][32 g][24 k]    12288  A-frag L2 (zero-padded)
#define OFF_BB  37120    // f32 [8o][3][32]          3072  b1,b2,W3 (zero-padded)
#define OFF_ZT  40192    // u16 [4wv][16 b][40]      5120  L1->L2 repack scratch
#define OFF_NS  45312    // u16 [64 b][8 o]          1024  noise bf16
#define OFF_OUT 46336    // f32 [64 b][8 o]          2048
#define SMEM_BYTES 48384 // 47.25 KB -> 3 blocks/CU

#define ZERO_OFF OFF_W1T
#define ZERO_DW  ((OFF_ZT + 5120 - OFF_W1T) / 4)   // 7168 dwords = 28/thread exact

__device__ __forceinline__ float fast_tanh(float x) {
    float e = __builtin_amdgcn_exp2f(x * 2.885390081777927f); // 2*log2(e)
    float r = __builtin_amdgcn_rcpf(1.0f + e);
    return 1.0f - 2.0f * r;
}
__device__ __forceinline__ unsigned short f2bf(float f) {
    unsigned u = __float_as_uint(f);
    return (unsigned short)((u + 0x8000u) >> 16);
}
__device__ __forceinline__ unsigned pkbf(float a, float b) {
    union { __hip_bfloat162 h; unsigned u; } p;
    p.h = __float22bfloat162_rn(make_float2(a, b));  // low half = a
    return p.u;
}
union frag_u { uint4 u4; bf16x8 v; };

__global__ __launch_bounds__(NTH, 3) void medil_fused(
    const float* __restrict__ x, const float* __restrict__ noise,
    const int* __restrict__ cause_idx,
    const float* __restrict__ W1, const float* __restrict__ b1,
    const float* __restrict__ W2, const float* __restrict__ b2,
    const float* __restrict__ W3, const float* __restrict__ b3,
    float* __restrict__ out)
{
    __shared__ __align__(16) char smem[SMEM_BYTES];

    const int tid = threadIdx.x;
    const int o0 = (blockIdx.x & 63) * TO;   // o fast: x tile reused across blocks in L2
    const int b0 = (blockIdx.x >> 6) * TB;

    // ---- phase 0: zero MFMA-padded regions (pads must be 0, never NaN) ----
    {
        unsigned* z = (unsigned*)(smem + ZERO_OFF);
        #pragma unroll
        for (int i = 0; i < ZERO_DW / NTH; ++i) z[tid + NTH * i] = 0u;
    }
    __syncthreads();

    // ---- phase 1: stage ----
    {   // weights: 32 threads per o
        const int ol = tid >> 5, t32 = tid & 31;
        const int o = o0 + ol;
        if (t32 < 20) {
            unsigned short* w1t = (unsigned short*)(smem + OFF_W1T) + ol * 512;
            #pragma unroll
            for (int k = 0; k < 9; ++k)      // W1T[h=t32][k]
                w1t[t32 * 16 + k] = f2bf(W1[(size_t)o * 180 + k * 20 + t32]);
            unsigned short* w2t = (unsigned short*)(smem + OFF_W2T) + ol * 768;
            #pragma unroll
            for (int h = 0; h < 20; ++h)     // W2T[g=t32][k=h]
                w2t[t32 * 24 + h] = f2bf(W2[(size_t)o * 400 + h * 20 + t32]);
            float* bb = (float*)(smem + OFF_BB) + ol * 96;
            bb[t32]      = b1[o * H_DIM + t32];
            bb[32 + t32] = b2[o * H_DIM + t32];
            bb[64 + t32] = W3[o * H_DIM + t32];
        }
    }
    {   // noise tile -> bf16 [64 b][8 o]
        const int b = tid >> 2, j = tid & 3;
        float2 nv = *(const float2*)(noise + (size_t)(b0 + b) * O_DIM + o0 + 2 * j);
        *(unsigned*)(smem + OFF_NS + b * 16 + j * 4) = pkbf(nv.x, nv.y);
    }
    {   // x tile -> bf16 pair-packed xp[colpair][b], pitch 65 dwords
        #pragma unroll
        for (int i = 0; i < 8; ++i) {
            int t = tid + NTH * i;           // 0..2047
            int r = t >> 5, c4 = t & 31;
            float4 v = *(const float4*)(x + (size_t)(b0 + r) * L_DIM + 4 * c4);
            *(unsigned*)(smem + OFF_XP + (2 * c4)     * 260 + r * 4) = pkbf(v.x, v.y);
            *(unsigned*)(smem + OFF_XP + (2 * c4 + 1) * 260 + r * 4) = pkbf(v.z, v.w);
        }
    }
    __syncthreads();

    const int lane = tid & 63;
    const int wv   = tid >> 6;
    const int l15  = lane & 15;   // C/D column = b within tile; A row m
    const int q    = lane >> 4;   // k-quad / C-D row group
    const bool q0 = (q == 0), q1 = (q == 1);
    char* zt_w = smem + OFF_ZT + wv * 1280;   // per-wave [16 b][80 B]

    #pragma unroll 1
    for (int oo = 0; oo < 2; ++oo) {
        const int ol = __builtin_amdgcn_readfirstlane(wv * 2 + oo);
        const int o  = o0 + ol;

        int c[8];                                  // wave-uniform -> SGPRs
        {
            const int* cip = cause_idx + (size_t)o * K_DIM;
            #pragma unroll
            for (int k = 0; k < 8; ++k) c[k] = cip[k];
        }
        const float b3v = b3[o];

        // A-frags (lane m=l15 / 16+l15, k-slice by q; pads zero, B kills k>=20)
        const int koff1 = (q & 1) * 16;
        const int koff2 = (q < 2 ? q : 2) * 16;
        frag_u a1a, a1b, a2a, a2b;
        a1a.u4 = *(const uint4*)(smem + OFF_W1T + ol * 1024 + l15 * 32 + koff1);
        a1b.u4 = *(const uint4*)(smem + OFF_W1T + ol * 1024 + (16 + l15) * 32 + koff1);
        a2a.u4 = *(const uint4*)(smem + OFF_W2T + ol * 1536 + l15 * 48 + koff2);
        a2b.u4 = *(const uint4*)(smem + OFF_W2T + ol * 1536 + (16 + l15) * 48 + koff2);

        const float* bb = (const float*)(smem + OFF_BB) + ol * 96;
        float4 b1q = *(const float4*)(bb + 4 * q);        // b1[4q+i]
        float4 b1u = *(const float4*)(bb + 16);           // b1[16..19]
        float4 b2q = *(const float4*)(bb + 32 + 4 * q);   // b2[4q+i]
        float4 b2u = *(const float4*)(bb + 48 + 4 * q);   // b2[16+4q+i] (pads 0)
        float4 w3q = *(const float4*)(bb + 64 + 4 * q);   // W3[4q+i]
        float4 w3u = *(const float4*)(bb + 80 + 4 * q);   // W3[16+4q+i] (pads 0)

        #pragma unroll 1
        for (int bt = 0; bt < 4; ++bt) {
            const int brow = bt * 16 + l15;

            // ---- B1 built in REGISTERS (no cross-lane deps): lane (l15,q)
            //      holds inp[k=8q..8q+7] for b-column l15. Gather columns are
            //      wave-uniform -> LDS broadcast reads (free).
            unsigned xv[8];
            #pragma unroll
            for (int k = 0; k < 8; ++k) {
                unsigned d = *(const unsigned*)(smem + OFF_XP + (c[k] >> 1) * 260 + brow * 4);
                xv[k] = (d >> ((c[k] & 1) * 16)) & 0xFFFFu;
            }
            unsigned nz = *(const unsigned short*)(smem + OFF_NS + brow * 16 + ol * 2);
            frag_u bf1;
            bf1.u4.x = q0 ? (nz | (xv[0] << 16)) : (q1 ? xv[7] : 0u);
            bf1.u4.y = q0 ? (xv[1] | (xv[2] << 16)) : 0u;
            bf1.u4.z = q0 ? (xv[3] | (xv[4] << 16)) : 0u;
            bf1.u4.w = q0 ? (xv[5] | (xv[6] << 16)) : 0u;

            // ---- layer 1 MFMA (transposed): z1[h][b] ----
            f32x4 zero = {0.f, 0.f, 0.f, 0.f};
            f32x4 c1a = __builtin_amdgcn_mfma_f32_16x16x32_bf16(a1a.v, bf1.v, zero, 0, 0, 0);
            f32x4 c1b = __builtin_amdgcn_mfma_f32_16x16x32_bf16(a1b.v, bf1.v, zero, 0, 0, 0);

            // ---- repack tanh(z1) into B2 layout via per-wave LDS scratch.
            //      Cross-lane data flow: fences pin compiler order; HW LDS is
            //      same-wave in-order.
            __asm__ volatile("" ::: "memory");
            {   // rows h=4q..4q+3 -> halfs 4q..4q+3
                float t0 = fast_tanh(c1a[0] + b1q.x);
                float t1 = fast_tanh(c1a[1] + b1q.y);
                float t2 = fast_tanh(c1a[2] + b1q.z);
                float t3 = fast_tanh(c1a[3] + b1q.w);
                uint2 pk = { pkbf(t0, t1), pkbf(t2, t3) };
                *(uint2*)(zt_w + l15 * 80 + q * 8) = pk;
            }
            if (q0) {   // rows h=16..19 live in q==0 lanes' c1b -> halfs 16..19
                float t0 = fast_tanh(c1b[0] + b1u.x);
                float t1 = fast_tanh(c1b[1] + b1u.y);
                float t2 = fast_tanh(c1b[2] + b1u.z);
                float t3 = fast_tanh(c1b[3] + b1u.w);
                uint2 pk = { pkbf(t0, t1), pkbf(t2, t3) };
                *(uint2*)(zt_w + l15 * 80 + 32) = pk;
            }
            __asm__ volatile("" ::: "memory");
            frag_u bf2;
            bf2.u4 = *(const uint4*)(zt_w + l15 * 80 + q * 16);  // halfs 20..31 stay 0

            // ---- layer 2 MFMA: z2[g][b] ----
            f32x4 c2a = __builtin_amdgcn_mfma_f32_16x16x32_bf16(a2a.v, bf2.v, zero, 0, 0, 0);
            f32x4 c2b = __builtin_amdgcn_mfma_f32_16x16x32_bf16(a2b.v, bf2.v, zero, 0, 0, 0);

            // ---- epilogue: tanh + W3 dot. Upper tile handled in-register:
            //      q>=1 lanes see c2b=0 (A2 rows 20..31 zeroed), b2u=0, w3u=0
            //      -> contribute exactly 0 through the shfl reduction.
            float s;
            s = fast_tanh(c2a[0] + b2q.x) * w3q.x;
            s = fmaf(fast_tanh(c2a[1] + b2q.y), w3q.y, s);
            s = fmaf(fast_tanh(c2a[2] + b2q.z), w3q.z, s);
            s = fmaf(fast_tanh(c2a[3] + b2q.w), w3q.w, s);
            s = fmaf(fast_tanh(c2b[0] + b2u.x), w3u.x, s);
            s = fmaf(fast_tanh(c2b[1] + b2u.y), w3u.y, s);
            s = fmaf(fast_tanh(c2b[2] + b2u.z), w3u.z, s);
            s = fmaf(fast_tanh(c2b[3] + b2u.w), w3u.w, s);
            s += __shfl_xor(s, 16);
            s += __shfl_xor(s, 32);
            s += b3v;
            if (lane < 16)
                *(float*)(smem + OFF_OUT + brow * 32 + ol * 4) = s;
        }
    }

    // ---- coalesced store ----
    __syncthreads();
    {
        const int b = tid >> 2, j = (tid & 3) * 2;
        float2 v = *(const float2*)(smem + OFF_OUT + b * 32 + j * 4);
        *(float2*)(out + (size_t)(b0 + b) * O_DIM + o0 + j) = v;
    }
}

extern "C" void kernel_launch(void* const* d_in, const int* in_sizes, int n_in,
                              void* d_out, int out_size, void* d_ws, size_t ws_size,
                              hipStream_t stream) {
    const float* x         = (const float*)d_in[0];
    const float* noise     = (const float*)d_in[1];
    const int*   cause_idx = (const int*)d_in[2];
    const float* W1        = (const float*)d_in[3];
    const float* b1        = (const float*)d_in[4];
    const float* W2        = (const float*)d_in[5];
    const float* b2        = (const float*)d_in[6];
    const float* W3        = (const float*)d_in[7];
    const float* b3        = (const float*)d_in[8];
    float* out = (float*)d_out;

    dim3 grid((B_TOT / TB) * (O_DIM / TO));   // 128 * 64 = 8192 blocks
    dim3 block(NTH);
    hipLaunchKernelGGL(medil_fused, grid, block, 0, stream,
                       x, noise, cause_idx, W1, b1, W2, b2, W3, b3, out);
}